// Round 6
// baseline (429.578 us; speedup 1.0000x reference)
//
#include <hip/hip_runtime.h>
#include <hip/hip_bf16.h>
#include <math.h>

// Problem constants (match reference)
#define T_TOK 1024
#define H_DIM 1024
#define I_DIM 512
#define E_NUM 32
#define K_TOP 4
#define G_NUM 8
#define TG_NUM 4
#define CAP 256              // C = 2*T*K/E
#define IS_DIM 1024          // I * NS
#define RSCALE 2.5f

#define MAXTILES 72          // 8 shared (M=128) + <=64 routed

// ws layout (byte offsets)
#define WS_CNT_OFF    0
#define WS_NT_OFF     128
#define WS_TILE_OFF   256        // int tiles[MAXTILES][4]
#define WS_EIDX_OFF   4096       // int eidx[T*K]
#define WS_WN_OFF     20480      // float wnorm[T*K]
#define WS_STOK_OFF   36864      // int slot_token[E*CAP]
#define WS_SW_OFF     69632      // float slot_w[E*CAP]
#define WS_XB_OFF     102400     // bf16 xb[T*H] (2 MB)
#define WS_ACT_OFF    (102400 + (size_t)T_TOK*H_DIM*2)           // bf16 act[E*CAP*I] (8 MB)
#define WS_ACTS_OFF   (WS_ACT_OFF + (size_t)E_NUM*CAP*I_DIM*2)   // bf16 acts[T*IS] (2 MB)

typedef __attribute__((ext_vector_type(8))) short short8v;
typedef __attribute__((ext_vector_type(4))) float f32x4;
typedef __attribute__((ext_vector_type(4))) unsigned uint4v;

__device__ __forceinline__ short f2bf(float f) {          // RNE, epilogue
    unsigned u = __float_as_uint(f);
    u += 0x7FFFu + ((u >> 16) & 1u);
    return (short)(u >> 16);
}
__device__ __forceinline__ unsigned pk2bf(float a, float b) {   // round-half-up
    unsigned ua = __float_as_uint(a) + 0x8000u;
    unsigned ub = __float_as_uint(b) + 0x8000u;
    return __builtin_amdgcn_perm(ub, ua, 0x07060302);
}
__device__ __forceinline__ uint4v pk8bf(float4 lo, float4 hi) {
    uint4v r; r.x = pk2bf(lo.x, lo.y); r.y = pk2bf(lo.z, lo.w);
    r.z = pk2bf(hi.x, hi.y); r.w = pk2bf(hi.z, hi.w); return r;
}
__device__ __forceinline__ float silu_(float g) { return g / (1.f + expf(-g)); }

#define LDSTRIDE 40   // shorts per LDS row (80 B, 16B-aligned)

// -------- x -> bf16 --------
__global__ __launch_bounds__(256) void xconv_kernel(const float* __restrict__ x,
                                                    short* __restrict__ xb) {
    const int i = (blockIdx.x * 256 + threadIdx.x) * 8;
    float4 a = *(const float4*)(x + i);
    float4 b = *(const float4*)(x + i + 4);
    *(uint4v*)(xb + i) = pk8bf(a, b);
}

// -------- gating --------
__global__ __launch_bounds__(256) void gate_kernel(
    const float* __restrict__ x, const float* __restrict__ gate_w,
    const float* __restrict__ e_bias,
    int* __restrict__ eidx, float* __restrict__ wnorm)
{
    __shared__ float xs[H_DIM];
    __shared__ float logits[E_NUM];
    const int t = blockIdx.x;
    const int tid = threadIdx.x;
    ((float4*)xs)[tid] = ((const float4*)(x + (size_t)t * H_DIM))[tid];
    __syncthreads();

    const int e = tid >> 3, sub = tid & 7;
    const float4* gw4 = (const float4*)(gate_w + (size_t)e * H_DIM + sub * 128);
    const float4* xr4 = (const float4*)(xs + sub * 128);
    float p = 0.f;
    #pragma unroll
    for (int h = 0; h < 32; ++h) {
        float4 a = xr4[h], b = gw4[h];
        p += a.x * b.x + a.y * b.y + a.z * b.z + a.w * b.w;
    }
    for (int off = 4; off; off >>= 1) p += __shfl_down(p, off, 8);
    if (sub == 0) logits[e] = p;
    __syncthreads();
    if (tid != 0) return;

    float sc[E_NUM], sfc[E_NUM];
    for (int i = 0; i < E_NUM; ++i) {
        sc[i] = 1.f / (1.f + expf(-logits[i]));
        sfc[i] = sc[i] + e_bias[i];
    }
    float gs[G_NUM];
    for (int g = 0; g < G_NUM; ++g) {
        float m1 = -1e30f, m2 = -1e30f;
        for (int j = 0; j < E_NUM / G_NUM; ++j) {
            float v = sfc[g * (E_NUM / G_NUM) + j];
            if (v > m1) { m2 = m1; m1 = v; } else if (v > m2) m2 = v;
        }
        gs[g] = m1 + m2;
    }
    bool gm[G_NUM];
    for (int g = 0; g < G_NUM; ++g) gm[g] = false;
    for (int it = 0; it < TG_NUM; ++it) {
        int best = -1; float bv = -1e30f;
        for (int g = 0; g < G_NUM; ++g) if (!gm[g] && gs[g] > bv) { bv = gs[g]; best = g; }
        gm[best] = true;
    }
    float sm[E_NUM];
    for (int i = 0; i < E_NUM; ++i) sm[i] = gm[i / (E_NUM / G_NUM)] ? sfc[i] : 0.0f;
    int idx[K_TOP]; float w[K_TOP]; float tsum = 0.f;
    for (int it = 0; it < K_TOP; ++it) {
        int best = 0; float bv = -1e30f;
        for (int i = 0; i < E_NUM; ++i) if (sm[i] > bv) { bv = sm[i]; best = i; }
        sm[best] = -1e30f;
        idx[it] = best; w[it] = sc[best]; tsum += w[it];
    }
    float inv = RSCALE / (tsum + 1e-20f);
    const int base = t * K_TOP;
    for (int it = 0; it < K_TOP; ++it) {
        eidx[base + it] = idx[it];
        wnorm[base + it] = w[it] * inv;
    }
}

// -------- deterministic capacity dispatch + unified tile-list (M=128) --------
__global__ __launch_bounds__(256) void assign_kernel(
    const int* __restrict__ eidx, const float* __restrict__ wnorm,
    int* __restrict__ cnt, int* __restrict__ slot_token, float* __restrict__ slot_w,
    int* __restrict__ ntiles, int* __restrict__ tiles)
{
    __shared__ int   se[T_TOK * K_TOP];
    __shared__ float swt[T_TOK * K_TOP];
    __shared__ int   scnt[E_NUM];
    const int tid = threadIdx.x;
    for (int i = tid; i < T_TOK * K_TOP; i += 256) { se[i] = eidx[i]; swt[i] = wnorm[i]; }
    __syncthreads();

    const int e = tid >> 3;
    const int seg = tid & 7;
    const int base = seg * 512;
    int c = 0;
    for (int i = 0; i < 512; ++i) c += (se[base + i] == e);
    int excl = 0, total = 0;
    for (int s = 0; s < 8; ++s) {
        int cs = __shfl(c, s, 8);
        total += cs;
        if (s < seg) excl += cs;
    }
    if (seg == 0) { cnt[e] = total; scnt[e] = total; }
    int pos = excl;
    for (int i = 0; i < 512; ++i) {
        if (se[base + i] == e) {
            if (pos < CAP) {
                slot_token[e * CAP + pos] = (base + i) >> 2;
                slot_w[e * CAP + pos] = swt[base + i];
            }
            ++pos;
        }
    }
    __syncthreads();
    if (tid == 0) {
        int nt = 0;
        for (int t0 = 0; t0 < T_TOK; t0 += 128) {            // shared tiles
            tiles[nt * 4] = -1; tiles[nt * 4 + 1] = t0; tiles[nt * 4 + 2] = 128; ++nt;
        }
        for (int ee = 0; ee < E_NUM; ++ee) {
            int n = min(scnt[ee], CAP);
            for (int r = 0; r < n; r += 128) {
                tiles[nt * 4] = ee; tiles[nt * 4 + 1] = r; tiles[nt * 4 + 2] = n; ++nt;
            }
        }
        *ntiles = nt;
    }
}

// ---------------- MFMA GEMM: block tile 128(M) x 128(B-rows), BK=32, LDS dbuf ---
#define WAVE_SETUP() \
    const int tid = threadIdx.x; const int lane = tid & 63; const int wid = tid >> 6; \
    const int wm = wid & 1, wn = wid >> 1; \
    const int lr16 = lane & 15, kc = lane >> 4; \
    const int srow = tid >> 1, kh = (tid & 1) * 16;   /* staging: row, 16-elem k-half */

#define DECL_ACC() f32x4 acc[4][4]; \
    _Pragma("unroll") for (int i_ = 0; i_ < 4; ++i_) \
    _Pragma("unroll") for (int j_ = 0; j_ < 4; ++j_) acc[i_][j_] = 0.f;

#define COMPUTE_4x4(Asb, Bsb) do { \
    short8v a_[4], b_[4]; \
    _Pragma("unroll") for (int mt = 0; mt < 4; ++mt) \
        a_[mt] = *(const short8v*)&(Asb)[(wm*64 + mt*16 + lr16)*LDSTRIDE + kc*8]; \
    _Pragma("unroll") for (int nt = 0; nt < 4; ++nt) \
        b_[nt] = *(const short8v*)&(Bsb)[(wn*64 + nt*16 + lr16)*LDSTRIDE + kc*8]; \
    _Pragma("unroll") for (int mt = 0; mt < 4; ++mt) \
    _Pragma("unroll") for (int nt = 0; nt < 4; ++nt) \
        acc[mt][nt] = __builtin_amdgcn_mfma_f32_16x16x32_bf16(a_[mt], b_[nt], acc[mt][nt], 0, 0, 0); \
} while (0)

// unified gate_up + SiLU*mul (routed + shared).  grid (16, MAXTILES)
__global__ __launch_bounds__(256, 3) void gu_all_kernel(
    const short* __restrict__ xb, const float* __restrict__ w_gate_up,
    const float* __restrict__ w_gus,
    const int* __restrict__ ntiles, const int* __restrict__ tiles,
    const int* __restrict__ slot_token, const float* __restrict__ slot_w,
    short* __restrict__ act, short* __restrict__ acts)
{
    if ((int)blockIdx.y >= *ntiles) return;
    const int e  = tiles[blockIdx.y * 4];
    const int r0 = tiles[blockIdx.y * 4 + 1];
    const int ne = tiles[blockIdx.y * 4 + 2];
    const bool sh = (e < 0);
    if (!sh && blockIdx.x >= I_DIM / 64) return;
    const int col0 = blockIdx.x * 64;

    __shared__ __align__(16) short As[2][128 * LDSTRIDE];
    __shared__ __align__(16) short Bs[2][128 * LDSTRIDE];
    __shared__ int   toks[128];
    __shared__ float sws[128];

    WAVE_SETUP();
    if (tid < 128) {
        if (sh) { toks[tid] = r0 + tid; sws[tid] = 1.f; }
        else {
            int p = r0 + tid; bool v = p < ne;
            toks[tid] = v ? slot_token[e * CAP + p] : 0;
            sws[tid]  = v ? slot_w[e * CAP + p] : 0.f;
        }
    }
    __syncthreads();

    const int IDim = sh ? IS_DIM : I_DIM;
    const float* wbase = sh ? w_gus : (w_gate_up + (size_t)e * (2 * I_DIM) * H_DIM);
    const int c = srow;
    const int wr = ((c >> 4) & 1) * IDim + col0 + ((c >> 5) << 4) + (c & 15);
    const short* aptr = xb + (size_t)toks[srow] * H_DIM + kh;
    const float* bptr = wbase + (size_t)wr * H_DIM + kh;
    const int off = srow * LDSTRIDE + kh;

    DECL_ACC();
    short8v cA0 = *(const short8v*)(aptr), cA1 = *(const short8v*)(aptr + 8);
    float4 cB0 = *(const float4*)(bptr),     cB1 = *(const float4*)(bptr + 4);
    float4 cB2 = *(const float4*)(bptr + 8), cB3 = *(const float4*)(bptr + 12);

    int buf = 0;
    for (int k0 = 0; k0 < H_DIM; k0 += 32) {
        short8v nA0, nA1; float4 nB0, nB1, nB2, nB3;
        const int k1 = k0 + 32;
        if (k1 < H_DIM) {
            nA0 = *(const short8v*)(aptr + k1); nA1 = *(const short8v*)(aptr + k1 + 8);
            nB0 = *(const float4*)(bptr + k1);     nB1 = *(const float4*)(bptr + k1 + 4);
            nB2 = *(const float4*)(bptr + k1 + 8); nB3 = *(const float4*)(bptr + k1 + 12);
        }
        *(short8v*)&As[buf][off]     = cA0;
        *(short8v*)&As[buf][off + 8] = cA1;
        *(uint4v*)&Bs[buf][off]      = pk8bf(cB0, cB1);
        *(uint4v*)&Bs[buf][off + 8]  = pk8bf(cB2, cB3);
        __syncthreads();
        COMPUTE_4x4(As[buf], Bs[buf]);
        buf ^= 1;
        cA0 = nA0; cA1 = nA1; cB0 = nB0; cB1 = nB1; cB2 = nB2; cB3 = nB3;
    }

    short* rowbase = sh ? (acts + (size_t)r0 * IS_DIM)
                        : (act + ((size_t)e * CAP + r0) * I_DIM);
    const int nmax = sh ? 128 : (ne - r0);
    #pragma unroll
    for (int mt = 0; mt < 4; ++mt) {
        #pragma unroll
        for (int q = 0; q < 2; ++q) {
            f32x4 g = acc[mt][2 * q], u = acc[mt][2 * q + 1];
            int colI = col0 + wn * 32 + q * 16 + lr16;
            #pragma unroll
            for (int i = 0; i < 4; ++i) {
                int rl = wm * 64 + mt * 16 + kc * 4 + i;
                if (rl < nmax) {
                    float s = sws[rl];
                    rowbase[(size_t)rl * IDim + colI] = f2bf(s * silu_(g[i]) * u[i]);
                }
            }
        }
    }
}

// unified down-proj + atomic scatter onto zeroed out.  grid (8, MAXTILES)
__global__ __launch_bounds__(256, 3) void down_all_kernel(
    const short* __restrict__ act, const short* __restrict__ acts,
    const float* __restrict__ w_down, const float* __restrict__ w_ds,
    const int* __restrict__ ntiles, const int* __restrict__ tiles,
    const int* __restrict__ slot_token, float* __restrict__ out)
{
    if ((int)blockIdx.y >= *ntiles) return;
    const int e  = tiles[blockIdx.y * 4];
    const int r0 = tiles[blockIdx.y * 4 + 1];
    const int ne = tiles[blockIdx.y * 4 + 2];
    const bool sh = (e < 0);
    const int h0 = blockIdx.x * 128;

    __shared__ __align__(16) short As[2][128 * LDSTRIDE];
    __shared__ __align__(16) short Bs[2][128 * LDSTRIDE];
    __shared__ int toks[128];

    WAVE_SETUP();
    if (tid < 128) {
        if (sh) toks[tid] = r0 + tid;
        else {
            int p = r0 + tid;
            toks[tid] = (p < ne) ? slot_token[e * CAP + p] : 0;
        }
    }
    __syncthreads();

    const int Kdim = sh ? IS_DIM : I_DIM;
    const short* aptr = (sh ? (acts + (size_t)(r0 + srow) * IS_DIM)
                            : (act + ((size_t)e * CAP + r0 + srow) * I_DIM)) + kh;
    const float* bptr = (sh ? w_ds : (w_down + (size_t)e * H_DIM * I_DIM))
                        + (size_t)(h0 + srow) * Kdim + kh;
    const int off = srow * LDSTRIDE + kh;

    DECL_ACC();
    short8v cA0 = *(const short8v*)(aptr), cA1 = *(const short8v*)(aptr + 8);
    float4 cB0 = *(const float4*)(bptr),     cB1 = *(const float4*)(bptr + 4);
    float4 cB2 = *(const float4*)(bptr + 8), cB3 = *(const float4*)(bptr + 12);

    int buf = 0;
    for (int k0 = 0; k0 < Kdim; k0 += 32) {
        short8v nA0, nA1; float4 nB0, nB1, nB2, nB3;
        const int k1 = k0 + 32;
        if (k1 < Kdim) {
            nA0 = *(const short8v*)(aptr + k1); nA1 = *(const short8v*)(aptr + k1 + 8);
            nB0 = *(const float4*)(bptr + k1);     nB1 = *(const float4*)(bptr + k1 + 4);
            nB2 = *(const float4*)(bptr + k1 + 8); nB3 = *(const float4*)(bptr + k1 + 12);
        }
        *(short8v*)&As[buf][off]     = cA0;
        *(short8v*)&As[buf][off + 8] = cA1;
        *(uint4v*)&Bs[buf][off]      = pk8bf(cB0, cB1);
        *(uint4v*)&Bs[buf][off + 8]  = pk8bf(cB2, cB3);
        __syncthreads();
        COMPUTE_4x4(As[buf], Bs[buf]);
        buf ^= 1;
        cA0 = nA0; cA1 = nA1; cB0 = nB0; cB1 = nB1; cB2 = nB2; cB3 = nB3;
    }

    const int nmax = sh ? 128 : (ne - r0);
    #pragma unroll
    for (int mt = 0; mt < 4; ++mt) {
        #pragma unroll
        for (int i = 0; i < 4; ++i) {
            int rl = wm * 64 + mt * 16 + kc * 4 + i;
            if (rl < nmax) {
                float* orow = out + (size_t)toks[rl] * H_DIM + h0 + wn * 64;
                #pragma unroll
                for (int nt = 0; nt < 4; ++nt)
                    atomicAdd(&orow[nt * 16 + lr16], acc[mt][nt][i]);
            }
        }
    }
}

extern "C" void kernel_launch(void* const* d_in, const int* in_sizes, int n_in,
                              void* d_out, int out_size, void* d_ws, size_t ws_size,
                              hipStream_t stream) {
    const float* x   = (const float*)d_in[0];
    const float* gw  = (const float*)d_in[1];
    const float* eb  = (const float*)d_in[2];
    const float* wgu = (const float*)d_in[3];
    const float* wd  = (const float*)d_in[4];
    const float* wgs = (const float*)d_in[5];
    const float* wds = (const float*)d_in[6];
    float* out = (float*)d_out;
    char* ws = (char*)d_ws;

    int*   cnt    = (int*)(ws + WS_CNT_OFF);
    int*   ntiles = (int*)(ws + WS_NT_OFF);
    int*   tiles  = (int*)(ws + WS_TILE_OFF);
    int*   eidx   = (int*)(ws + WS_EIDX_OFF);
    float* wnorm  = (float*)(ws + WS_WN_OFF);
    int*   stok   = (int*)(ws + WS_STOK_OFF);
    float* sw     = (float*)(ws + WS_SW_OFF);
    short* xb     = (short*)(ws + WS_XB_OFF);
    short* act    = (short*)(ws + WS_ACT_OFF);
    short* acts   = (short*)(ws + WS_ACTS_OFF);

    hipMemsetAsync(out, 0, (size_t)T_TOK * H_DIM * sizeof(float), stream);
    xconv_kernel<<<T_TOK * H_DIM / (256 * 8), 256, 0, stream>>>(x, xb);
    gate_kernel<<<T_TOK, 256, 0, stream>>>(x, gw, eb, eidx, wnorm);
    assign_kernel<<<1, 256, 0, stream>>>(eidx, wnorm, cnt, stok, sw, ntiles, tiles);
    gu_all_kernel<<<dim3(IS_DIM / 64, MAXTILES), 256, 0, stream>>>(
        xb, wgu, wgs, ntiles, tiles, stok, sw, act, acts);
    down_all_kernel<<<dim3(H_DIM / 128, MAXTILES), 256, 0, stream>>>(
        act, acts, wd, wds, ntiles, tiles, stok, out);
}